// Round 12
// baseline (1402.655 us; speedup 1.0000x reference)
//
#include <hip/hip_runtime.h>

#define N_NODES 100000
#define N_EDGES 300000
#define N_GRAPHS 2048
#define IN_DIM 38
#define HID 256
#define LAYERS 5
#define BN_EPS 1e-5f

#define SCAN_CHUNK 512
#define N_CHUNKS ((N_NODES + SCAN_CHUNK - 1) / SCAN_CHUNK)  // 196

// activation storage: split bf16 planes, row stride 512 ushorts:
//   buf[m*512 + c]       = hi bf16 bits of channel c
//   buf[m*512 + 256 + c] = lo bf16 bits (truncated residual)
#define ROW_PAD 128

typedef unsigned short u16;
typedef __attribute__((ext_vector_type(8))) short short8;       // 8 bf16 = 4 VGPR
typedef __attribute__((ext_vector_type(4))) unsigned short ushortx4;
typedef __attribute__((ext_vector_type(4))) float floatx4;      // MFMA acc

__device__ __forceinline__ unsigned short bf16_rne(float f) {
    unsigned int u = __float_as_uint(f);
    unsigned int r = (u + 0x7fffu + ((u >> 16) & 1u)) >> 16;
    return (unsigned short)r;
}
__device__ __forceinline__ float uf(unsigned short b) {
    return __uint_as_float((unsigned int)b << 16);
}
__device__ __forceinline__ void split_bf16(float v, unsigned short& hi,
                                           unsigned short& lo) {
    hi = bf16_rne(v);
    float hf = __uint_as_float((unsigned int)hi << 16);
    lo = (unsigned short)(__float_as_uint(v - hf) >> 16);  // truncated residual
}

// ---------------- projection: h = x @ Wp + bp  ([N,38]@[38,256]) -------------
#define PROJ_CH 64
__global__ __launch_bounds__(256) void proj_kernel(
    const float* __restrict__ x, const float* __restrict__ Wp,
    const float* __restrict__ bp, u16* __restrict__ h) {
    __shared__ float xs[PROJ_CH * IN_DIM];
    int t = threadIdx.x;
    float w[IN_DIM];
#pragma unroll
    for (int k = 0; k < IN_DIM; k++) w[k] = Wp[k * HID + t];
    float b = bp[t];
    int n0 = blockIdx.x * PROJ_CH;
    int count = min(PROJ_CH, N_NODES - n0);
    int total = count * IN_DIM;
    const float* xbase = x + (size_t)n0 * IN_DIM;
    for (int i = t; i < total; i += 256) xs[i] = xbase[i];
    __syncthreads();
    for (int n = 0; n < count; n++) {
        float acc = b;
        const float* xr = &xs[n * IN_DIM];
#pragma unroll
        for (int k = 0; k < IN_DIM; k++) acc = fmaf(xr[k], w[k], acc);
        unsigned short hb, lb;
        split_bf16(acc, hb, lb);
        h[(size_t)(n0 + n) * 512 + t] = hb;
        h[(size_t)(n0 + n) * 512 + 256 + t] = lb;
    }
}

// ---------------- CSR build --------------------------------------------------
__global__ __launch_bounds__(256) void hist_kernel(const int* __restrict__ ei,
                                                   int* __restrict__ deg) {
    int e = blockIdx.x * 256 + threadIdx.x;
    if (e < N_EDGES) atomicAdd(&deg[ei[N_EDGES + e]], 1);
}

__global__ __launch_bounds__(256) void scan1_kernel(const int* __restrict__ deg,
                                                    int* __restrict__ offs,
                                                    int* __restrict__ blocksums) {
    __shared__ int s[SCAN_CHUNK];
    int base = blockIdx.x * SCAN_CHUNK;
    int t = threadIdx.x;
    int i0 = t, i1 = t + 256;
    int g0 = base + i0, g1 = base + i1;
    int o0 = (g0 < N_NODES) ? deg[g0] : 0;
    int o1 = (g1 < N_NODES) ? deg[g1] : 0;
    s[i0] = o0;
    s[i1] = o1;
    __syncthreads();
    for (int off = 1; off < SCAN_CHUNK; off <<= 1) {
        int v0 = (i0 >= off) ? s[i0 - off] : 0;
        int v1 = (i1 >= off) ? s[i1 - off] : 0;
        __syncthreads();
        s[i0] += v0;
        s[i1] += v1;
        __syncthreads();
    }
    if (g0 < N_NODES) offs[g0] = s[i0] - o0;
    if (g1 < N_NODES) offs[g1] = s[i1] - o1;
    if (t == 0) blocksums[blockIdx.x] = s[SCAN_CHUNK - 1];
}

__global__ __launch_bounds__(256) void scan2_kernel(int* __restrict__ blocksums) {
    __shared__ int s[256];
    int t = threadIdx.x;
    int o = (t < N_CHUNKS) ? blocksums[t] : 0;
    s[t] = o;
    __syncthreads();
    for (int off = 1; off < 256; off <<= 1) {
        int v = (t >= off) ? s[t - off] : 0;
        __syncthreads();
        s[t] += v;
        __syncthreads();
    }
    if (t < N_CHUNKS) blocksums[t] = s[t] - o;
}

__global__ __launch_bounds__(256) void scan3_kernel(int* __restrict__ offs,
                                                    const int* __restrict__ blocksums,
                                                    int* __restrict__ cursor) {
    int g = blockIdx.x * 256 + threadIdx.x;
    if (g < N_NODES) {
        int v = offs[g] + blocksums[g / SCAN_CHUNK];
        offs[g] = v;
        cursor[g] = v;
    }
    if (g == 0) offs[N_NODES] = N_EDGES;
}

__global__ __launch_bounds__(256) void fill_kernel(const int* __restrict__ ei,
                                                   int* __restrict__ cursor,
                                                   int* __restrict__ csr_src) {
    int e = blockIdx.x * 256 + threadIdx.x;
    if (e < N_EDGES) {
        int src = ei[e];
        int dst = ei[N_EDGES + e];
        int pos = atomicAdd(&cursor[dst], 1);
        csr_src[pos] = src;
    }
}

// ---------------- weight packing: fragment-order bf16 hi/lo ------------------
__global__ __launch_bounds__(256) void packW_kernel(const float* __restrict__ W1s,
                                                    const float* __restrict__ W2s,
                                                    short8* __restrict__ Wpk8) {
    int id = blockIdx.x * 256 + threadIdx.x;  // < 81920
    int lane = id & 63;
    int fid = (id >> 6) & 127;
    int w = id >> 13;  // 0..9
    int kt = fid >> 4, nt = fid & 15;
    const float* Wsrc = (w < 5) ? W1s + (size_t)w * HID * HID
                                : W2s + (size_t)(w - 5) * HID * HID;
    int k0 = kt * 32 + ((lane >> 4) << 3);
    int n = nt * 16 + (lane & 15);
    short8 hi, lo;
#pragma unroll
    for (int e = 0; e < 8; e++) {
        float v = Wsrc[(size_t)(k0 + e) * HID + n];
        unsigned short hb, lb;
        split_bf16(v, hb, lb);
        hi[e] = (short)hb;
        lo[e] = (short)lb;
    }
    size_t base = (size_t)w * 16384;
    Wpk8[base + (size_t)((0 * 8 + kt) * 16 + nt) * 64 + lane] = hi;
    Wpk8[base + (size_t)((1 * 8 + kt) * 16 + nt) * 64 + lane] = lo;
}

// ------- fused GIN layer: gather + MLP(2 GEMMs) + BN stats, one kernel -------
// zout = (relu( gather(zin) @ W1 + b1 )) @ W2 + b2      (+ column sums/sumsq)
// gather(z)[i] = (1+eps)*f(z[i]) + sum_{j->i} f(z[j]);  f = BN(l-1)+relu (l>0)
// BM=64, 4 waves; wave w owns nodes w*16..w*16+15 in gather (mt=w) and output
// cols w*64..+63 in both GEMM stages. LDS = 64 KB, 4-phase temporal reuse:
//   phase 0: Zf (gathered tile, A-frag split layout, 64 frags x 1KB)
//   phase 1: stage-1 K-loop reads Zf (barrier-free, fully unrolled)
//   phase 2: Hf (H tile, same layout) reuses the region
//   phase 3: cf (64x256 fp32) reuses the region for the transpose epilogue
__global__ __launch_bounds__(256, 2) void fused_layer_kernel(
    const u16* __restrict__ zin, const int* __restrict__ offs,
    const int* __restrict__ csr_src, const float* __restrict__ eps, int layer,
    const float* __restrict__ scale, const float* __restrict__ shift, int useBN,
    const short8* __restrict__ W1m, const float* __restrict__ b1,
    const short8* __restrict__ W2m, const float* __restrict__ b2,
    u16* __restrict__ zout, int M,
    float* __restrict__ sums, float* __restrict__ sumsq) {
    __shared__ char lds[65536];
    short8* Zf8 = (short8*)lds;  // phase 0/1: 64 frags
    u16* Zfu = (u16*)lds;
    u16* Hf = (u16*)lds;         // phase 2
    float* cf = (float*)lds;     // phase 3
    int t = threadIdx.x;
    int lane = t & 63;
    int w = t >> 6;
    int m0 = blockIdx.x * 64;
    int col15 = lane & 15;
    int rgrp = lane >> 4;

    // ---------------- phase 0: gather 64 rows into Zf ----------------------
    {
        float s = 1.0f + eps[layer];
        int c0 = lane * 4;
        float4 sc = make_float4(1.f, 1.f, 1.f, 1.f);
        float4 sh = make_float4(0.f, 0.f, 0.f, 0.f);
        if (useBN) {
            sc = *(const float4*)&scale[c0];
            sh = *(const float4*)&shift[c0];
        }
        // frag coords for this lane's 4 channels
        int ki = c0 >> 6;
        int ktl = (c0 >> 5) & 1;
        int colg = (c0 >> 3) & 3;
        int e = c0 & 7;  // 0 or 4
        for (int n = 0; n < 16; n++) {
            int node = m0 + w * 16 + n;
            float a0 = 0.f, a1 = 0.f, a2 = 0.f, a3 = 0.f;
            if (node < M) {
                ushortx4 hi = *(const ushortx4*)&zin[(size_t)node * 512 + c0];
                ushortx4 lo =
                    *(const ushortx4*)&zin[(size_t)node * 512 + 256 + c0];
                a0 = uf(hi[0]) + uf(lo[0]);
                a1 = uf(hi[1]) + uf(lo[1]);
                a2 = uf(hi[2]) + uf(lo[2]);
                a3 = uf(hi[3]) + uf(lo[3]);
                if (useBN) {
                    a0 = fmaxf(a0 * sc.x + sh.x, 0.f);
                    a1 = fmaxf(a1 * sc.y + sh.y, 0.f);
                    a2 = fmaxf(a2 * sc.z + sh.z, 0.f);
                    a3 = fmaxf(a3 * sc.w + sh.w, 0.f);
                }
                a0 *= s; a1 *= s; a2 *= s; a3 *= s;
                int beg = offs[node], end = offs[node + 1];
                for (int ed = beg; ed < end; ed++) {
                    int src = csr_src[ed];
                    ushortx4 vh = *(const ushortx4*)&zin[(size_t)src * 512 + c0];
                    ushortx4 vl =
                        *(const ushortx4*)&zin[(size_t)src * 512 + 256 + c0];
                    float v0 = uf(vh[0]) + uf(vl[0]);
                    float v1 = uf(vh[1]) + uf(vl[1]);
                    float v2 = uf(vh[2]) + uf(vl[2]);
                    float v3 = uf(vh[3]) + uf(vl[3]);
                    if (useBN) {
                        v0 = fmaxf(v0 * sc.x + sh.x, 0.f);
                        v1 = fmaxf(v1 * sc.y + sh.y, 0.f);
                        v2 = fmaxf(v2 * sc.z + sh.z, 0.f);
                        v3 = fmaxf(v3 * sc.w + sh.w, 0.f);
                    }
                    a0 += v0; a1 += v1; a2 += v2; a3 += v3;
                }
            }
            ushortx4 ho, lo4;
            unsigned short hb, lb;
            split_bf16(a0, hb, lb); ho[0] = hb; lo4[0] = lb;
            split_bf16(a1, hb, lb); ho[1] = hb; lo4[1] = lb;
            split_bf16(a2, hb, lb); ho[2] = hb; lo4[2] = lb;
            split_bf16(a3, hb, lb); ho[3] = hb; lo4[3] = lb;
            int la = n + 16 * colg;
            int gh = ki * 8 + ktl * 4 + w;        // p=0 frag
            *(ushortx4*)&Zfu[((gh)*64 + la) * 8 + e] = ho;
            *(ushortx4*)&Zfu[((32 + gh) * 64 + la) * 8 + e] = lo4;
        }
    }
    __syncthreads();

    // ---------------- phase 1: acc = Zf @ W1 (barrier-free) ----------------
    floatx4 acc[4][4];
#pragma unroll
    for (int i = 0; i < 4; i++)
#pragma unroll
        for (int j = 0; j < 4; j++) acc[i][j] = (floatx4)0.0f;

#pragma unroll
    for (int ki = 0; ki < 4; ki++) {
#pragma unroll
        for (int ktl = 0; ktl < 2; ktl++) {
            short8 bb0[4], bb1[4];
#pragma unroll
            for (int j = 0; j < 4; j++) {
                bb0[j] = W1m[((size_t)(0 * 8 + ki * 2 + ktl) * 16 + (w * 4 + j)) *
                                 64 +
                             lane];
                bb1[j] = W1m[((size_t)(1 * 8 + ki * 2 + ktl) * 16 + (w * 4 + j)) *
                                 64 +
                             lane];
            }
            short8 ah[4], al[4];
#pragma unroll
            for (int mt = 0; mt < 4; mt++) {
                ah[mt] = Zf8[(ki * 8 + ktl * 4 + mt) * 64 + lane];
                al[mt] = Zf8[(32 + ki * 8 + ktl * 4 + mt) * 64 + lane];
            }
#pragma unroll
            for (int i = 0; i < 4; i++)
#pragma unroll
                for (int j = 0; j < 4; j++) {
                    acc[i][j] = __builtin_amdgcn_mfma_f32_16x16x32_bf16(
                        ah[i], bb0[j], acc[i][j], 0, 0, 0);
                    acc[i][j] = __builtin_amdgcn_mfma_f32_16x16x32_bf16(
                        ah[i], bb1[j], acc[i][j], 0, 0, 0);
                    acc[i][j] = __builtin_amdgcn_mfma_f32_16x16x32_bf16(
                        al[i], bb0[j], acc[i][j], 0, 0, 0);
                }
        }
    }
    __syncthreads();  // all Zf reads done; Hf takes over the region

    // ---------------- phase 2: H = relu(acc + b1) -> A-frag split LDS ------
#pragma unroll
    for (int j = 0; j < 4; j++) {
        int col = w * 64 + j * 16 + col15;
        float bv = b1[col];
        int kt2 = col >> 5;
        int colg = (col & 31) >> 3;
        int e = col & 7;
#pragma unroll
        for (int i = 0; i < 4; i++) {
            int lane_a = rgrp * 4 + colg * 16;
#pragma unroll
            for (int r = 0; r < 4; r++) {
                float v = fmaxf(acc[i][j][r] + bv, 0.0f);
                unsigned short hb, lb;
                split_bf16(v, hb, lb);
                Hf[(((0 * 8 + kt2) * 4 + i) * 64 + lane_a + r) * 8 + e] = hb;
                Hf[(((1 * 8 + kt2) * 4 + i) * 64 + lane_a + r) * 8 + e] = lb;
            }
        }
    }
    __syncthreads();

    // ---------------- phase 2b: acc2 = H @ W2 (barrier-free) ---------------
    floatx4 acc2[4][4];
#pragma unroll
    for (int i = 0; i < 4; i++)
#pragma unroll
        for (int j = 0; j < 4; j++) acc2[i][j] = (floatx4)0.0f;

#pragma unroll
    for (int kj = 0; kj < 8; kj++) {
        short8 bb2[2][4];
#pragma unroll
        for (int p = 0; p < 2; p++)
#pragma unroll
            for (int j = 0; j < 4; j++)
                bb2[p][j] =
                    W2m[((size_t)(p * 8 + kj) * 16 + (w * 4 + j)) * 64 + lane];
        short8 ah2[4], al2[4];
#pragma unroll
        for (int mt = 0; mt < 4; mt++) {
            ah2[mt] = *(short8*)&Hf[(((0 * 8 + kj) * 4 + mt) * 64 + lane) * 8];
            al2[mt] = *(short8*)&Hf[(((1 * 8 + kj) * 4 + mt) * 64 + lane) * 8];
        }
#pragma unroll
        for (int i = 0; i < 4; i++)
#pragma unroll
            for (int j = 0; j < 4; j++) {
                acc2[i][j] = __builtin_amdgcn_mfma_f32_16x16x32_bf16(
                    ah2[i], bb2[0][j], acc2[i][j], 0, 0, 0);
                acc2[i][j] = __builtin_amdgcn_mfma_f32_16x16x32_bf16(
                    ah2[i], bb2[1][j], acc2[i][j], 0, 0, 0);
                acc2[i][j] = __builtin_amdgcn_mfma_f32_16x16x32_bf16(
                    al2[i], bb2[0][j], acc2[i][j], 0, 0, 0);
            }
    }
    __syncthreads();  // Hf reads done; cf reuses the region

    // ---------------- phase 3: stats + LDS transpose + split write ---------
#pragma unroll
    for (int j = 0; j < 4; j++) {
        int col = w * 64 + j * 16 + col15;
        float bv = b2[col];
        float csum = 0.f, csq = 0.f;
#pragma unroll
        for (int i = 0; i < 4; i++) {
            int rowb = i * 16 + rgrp * 4;
#pragma unroll
            for (int r = 0; r < 4; r++) {
                float v = acc2[i][j][r] + bv;
                cf[(rowb + r) * 256 + col] = v;
                if (m0 + rowb + r < M) {
                    csum += v;
                    csq += v * v;
                }
            }
        }
        csum += __shfl_xor(csum, 16);
        csum += __shfl_xor(csum, 32);
        csq += __shfl_xor(csq, 16);
        csq += __shfl_xor(csq, 32);
        if (rgrp == 0) {
            atomicAdd(&sums[col], csum);
            atomicAdd(&sumsq[col], csq);
        }
    }
    __syncthreads();
#pragma unroll
    for (int k = 0; k < 16; k++) {
        int fi = (k * 256 + t) * 4;  // flat float idx in 64x256 tile
        int row = fi >> 8, colc = fi & 255;
        int m = m0 + row;
        if (m >= M) continue;
        float4 v4 = *(float4*)&cf[fi];
        ushortx4 h4, l4;
        unsigned short hb, lb;
        split_bf16(v4.x, hb, lb); h4[0] = hb; l4[0] = lb;
        split_bf16(v4.y, hb, lb); h4[1] = hb; l4[1] = lb;
        split_bf16(v4.z, hb, lb); h4[2] = hb; l4[2] = lb;
        split_bf16(v4.w, hb, lb); h4[3] = hb; l4[3] = lb;
        *(ushortx4*)&zout[(size_t)m * 512 + colc] = h4;
        *(ushortx4*)&zout[(size_t)m * 512 + 256 + colc] = l4;
    }
}

__global__ void bnparams_kernel(const float* __restrict__ sums,
                                const float* __restrict__ sumsq,
                                const float* __restrict__ gammas,
                                const float* __restrict__ betas, int layer,
                                float* __restrict__ scale,
                                float* __restrict__ shift) {
    int c = threadIdx.x;
    float mu = sums[c] / (float)N_NODES;
    float var = sumsq[c] / (float)N_NODES - mu * mu;
    float rs = rsqrtf(var + BN_EPS);
    float g = gammas[layer * HID + c];
    scale[c] = rs * g;
    shift[c] = betas[layer * HID + c] - mu * rs * g;
}

// ---------------- pooling (batch sorted), fused final BN+relu ----------------
__global__ __launch_bounds__(256) void bounds_kernel(const int* __restrict__ batch,
                                                     int* __restrict__ start) {
    int g = blockIdx.x * 256 + threadIdx.x;
    if (g > N_GRAPHS) return;
    int lo = 0, hi = N_NODES;
    while (lo < hi) {
        int mid = (lo + hi) >> 1;
        if (batch[mid] < g) lo = mid + 1;
        else hi = mid;
    }
    start[g] = lo;
}

__global__ __launch_bounds__(256) void segpool_kernel(
    const u16* __restrict__ z, const int* __restrict__ start,
    const float* __restrict__ scale, const float* __restrict__ shift,
    float* __restrict__ pooled) {
    int g = blockIdx.x;
    int c = threadIdx.x;
    float sc = scale[c], sh = shift[c];
    int beg = start[g], end = start[g + 1];
    float s = 0.f;
    for (int n = beg; n < end; n++) {
        float v = uf(z[(size_t)n * 512 + c]) + uf(z[(size_t)n * 512 + 256 + c]);
        s += fmaxf(v * sc + sh, 0.f);
    }
    float inv = 1.0f / fmaxf((float)(end - beg), 1.0f);
    pooled[(size_t)g * HID + c] = s * inv;
}

// ---------------- readout ----------------------------------------------------
__global__ __launch_bounds__(256) void readout_kernel(
    const float* __restrict__ pooled, const float* __restrict__ Wr1,
    const float* __restrict__ br1, const float* __restrict__ Wr2,
    const float* __restrict__ br2, float* __restrict__ out) {
    __shared__ float p[HID];
    __shared__ float red[4];
    int g = blockIdx.x;
    int c = threadIdx.x;
    p[c] = pooled[(size_t)g * HID + c];
    __syncthreads();
    float acc = br1[c];
    for (int k = 0; k < HID; k++) acc += p[k] * Wr1[k * HID + c];
    acc = fmaxf(acc, 0.f);
    float v = acc * Wr2[c];
#pragma unroll
    for (int off = 32; off > 0; off >>= 1) v += __shfl_down(v, off, 64);
    if ((c & 63) == 0) red[c >> 6] = v;
    __syncthreads();
    if (c == 0) out[g] = red[0] + red[1] + red[2] + red[3] + br2[0];
}

extern "C" void kernel_launch(void* const* d_in, const int* in_sizes, int n_in,
                              void* d_out, int out_size, void* d_ws, size_t ws_size,
                              hipStream_t stream) {
    const float* x      = (const float*)d_in[0];
    const int*   ei     = (const int*)d_in[1];
    const int*   batch  = (const int*)d_in[2];
    const float* Wp     = (const float*)d_in[3];
    const float* bp     = (const float*)d_in[4];
    const float* eps    = (const float*)d_in[5];
    const float* W1s    = (const float*)d_in[6];
    const float* b1s    = (const float*)d_in[7];
    const float* W2s    = (const float*)d_in[8];
    const float* b2s    = (const float*)d_in[9];
    const float* gammas = (const float*)d_in[10];
    const float* betas  = (const float*)d_in[11];
    const float* Wr1    = (const float*)d_in[12];
    const float* br1    = (const float*)d_in[13];
    const float* Wr2    = (const float*)d_in[14];
    const float* br2    = (const float*)d_in[15];
    float* out = (float*)d_out;

    const size_t ROWS = (size_t)N_NODES + ROW_PAD;
    u16* bufA     = (u16*)d_ws;                  // ROWS*512 u16
    u16* bufB     = bufA + ROWS * 512;
    short8* Wpk8  = (short8*)(bufB + ROWS * 512);  // 10*16384 short8 = 2.62 MB
    float* sums   = (float*)(Wpk8 + 10 * 16384);
    float* sumsq  = sums + HID;
    float* scale  = sumsq + HID;
    float* shift  = scale + HID;
    float* pooled = shift + HID;
    int* start     = (int*)(pooled + (size_t)N_GRAPHS * HID);  // N_GRAPHS+1
    int* deg       = start + N_GRAPHS + 1;
    int* offs      = deg + N_NODES;        // N_NODES+1
    int* cursor    = offs + N_NODES + 1;
    int* csr_src   = cursor + N_NODES;
    int* blocksums = csr_src + N_EDGES;    // N_CHUNKS

    // ---- CSR build + weight packing (once per launch) ----
    hipMemsetAsync(deg, 0, N_NODES * sizeof(int), stream);
    hist_kernel<<<(N_EDGES + 255) / 256, 256, 0, stream>>>(ei, deg);
    scan1_kernel<<<N_CHUNKS, 256, 0, stream>>>(deg, offs, blocksums);
    scan2_kernel<<<1, 256, 0, stream>>>(blocksums);
    scan3_kernel<<<(N_NODES + 255) / 256, 256, 0, stream>>>(offs, blocksums,
                                                            cursor);
    fill_kernel<<<(N_EDGES + 255) / 256, 256, 0, stream>>>(ei, cursor, csr_src);
    packW_kernel<<<320, 256, 0, stream>>>(W1s, W2s, Wpk8);
    bounds_kernel<<<(N_GRAPHS + 1 + 255) / 256, 256, 0, stream>>>(batch, start);

    // h0 = x @ Wp + bp  -> bufA (split bf16)
    proj_kernel<<<(N_NODES + PROJ_CH - 1) / PROJ_CH, 256, 0, stream>>>(x, Wp, bp,
                                                                       bufA);

    // Ping-pong: fused reads cur (random rows) and writes nxt -> must not alias.
    u16* cur = bufA;
    u16* nxt = bufB;
    const int MLP_BLOCKS = (N_NODES + 63) / 64;  // 1563
    for (int l = 0; l < LAYERS; l++) {
        hipMemsetAsync(sums, 0, 2 * HID * sizeof(float), stream);
        fused_layer_kernel<<<MLP_BLOCKS, 256, 0, stream>>>(
            cur, offs, csr_src, eps, l, scale, shift, l > 0 ? 1 : 0,
            Wpk8 + (size_t)l * 16384, b1s + l * HID,
            Wpk8 + (size_t)(5 + l) * 16384, b2s + l * HID, nxt, N_NODES,
            sums, sumsq);
        bnparams_kernel<<<1, HID, 0, stream>>>(sums, sumsq, gammas, betas, l,
                                               scale, shift);
        u16* tmp = cur; cur = nxt; nxt = tmp;
    }

    // cur holds z4 (pre-BN, split); segpool applies BN(4)+relu inline
    segpool_kernel<<<N_GRAPHS, 256, 0, stream>>>(cur, start, scale, shift,
                                                 pooled);
    readout_kernel<<<N_GRAPHS, 256, 0, stream>>>(pooled, Wr1, br1, Wr2, br2, out);
}

// Round 13
// 1109.491 us; speedup vs baseline: 1.2642x; 1.2642x over previous
//
#include <hip/hip_runtime.h>

#define N_NODES 100000
#define N_EDGES 300000
#define N_GRAPHS 2048
#define IN_DIM 38
#define HID 256
#define LAYERS 5
#define BN_EPS 1e-5f

#define SCAN_CHUNK 512
#define N_CHUNKS ((N_NODES + SCAN_CHUNK - 1) / SCAN_CHUNK)  // 196

// activation storage: split bf16 planes, row stride 512 ushorts:
//   buf[m*512 + c]       = hi bf16 bits of channel c
//   buf[m*512 + 256 + c] = lo bf16 bits (truncated residual)
#define ROW_PAD 128

typedef unsigned short u16;
typedef __attribute__((ext_vector_type(8))) short short8;       // 8 bf16 = 4 VGPR
typedef __attribute__((ext_vector_type(4))) unsigned short ushortx4;
typedef __attribute__((ext_vector_type(4))) float floatx4;      // MFMA acc

__device__ __forceinline__ unsigned short bf16_rne(float f) {
    unsigned int u = __float_as_uint(f);
    unsigned int r = (u + 0x7fffu + ((u >> 16) & 1u)) >> 16;
    return (unsigned short)r;
}
__device__ __forceinline__ float uf(unsigned short b) {
    return __uint_as_float((unsigned int)b << 16);
}
__device__ __forceinline__ void split_bf16(float v, unsigned short& hi,
                                           unsigned short& lo) {
    hi = bf16_rne(v);
    float hf = __uint_as_float((unsigned int)hi << 16);
    lo = (unsigned short)(__float_as_uint(v - hf) >> 16);  // truncated residual
}
// async 16B global -> LDS (HW dest = wave-uniform base + lane*16)
__device__ __forceinline__ void load16_to_lds(const void* g, void* l) {
    __builtin_amdgcn_global_load_lds(
        (const __attribute__((address_space(1))) unsigned int*)g,
        (__attribute__((address_space(3))) unsigned int*)l, 16, 0, 0);
}
// BN scale/shift for channel c from per-layer sums/sumsq
__device__ __forceinline__ void bn_params(const float* sums, const float* sumsq,
                                          const float* gammas,
                                          const float* betas, int c, float& sc,
                                          float& sh) {
    const float invN = 1.0f / (float)N_NODES;
    float mu = sums[c] * invN;
    float var = sumsq[c] * invN - mu * mu;
    float rs = rsqrtf(var + BN_EPS);
    float g = gammas[c];
    sc = rs * g;
    sh = betas[c] - mu * rs * g;
}

// ---------------- projection: h = x @ Wp + bp  ([N,38]@[38,256]) -------------
#define PROJ_CH 64
__global__ __launch_bounds__(256) void proj_kernel(
    const float* __restrict__ x, const float* __restrict__ Wp,
    const float* __restrict__ bp, u16* __restrict__ h) {
    __shared__ float xs[PROJ_CH * IN_DIM];
    int t = threadIdx.x;
    float w[IN_DIM];
#pragma unroll
    for (int k = 0; k < IN_DIM; k++) w[k] = Wp[k * HID + t];
    float b = bp[t];
    int n0 = blockIdx.x * PROJ_CH;
    int count = min(PROJ_CH, N_NODES - n0);
    int total = count * IN_DIM;
    const float* xbase = x + (size_t)n0 * IN_DIM;
    for (int i = t; i < total; i += 256) xs[i] = xbase[i];
    __syncthreads();
    for (int n = 0; n < count; n++) {
        float acc = b;
        const float* xr = &xs[n * IN_DIM];
#pragma unroll
        for (int k = 0; k < IN_DIM; k++) acc = fmaf(xr[k], w[k], acc);
        unsigned short hb, lb;
        split_bf16(acc, hb, lb);
        h[(size_t)(n0 + n) * 512 + t] = hb;
        h[(size_t)(n0 + n) * 512 + 256 + t] = lb;
    }
}

// ---------------- CSR build --------------------------------------------------
__global__ __launch_bounds__(256) void hist_kernel(const int* __restrict__ ei,
                                                   int* __restrict__ deg) {
    int e = blockIdx.x * 256 + threadIdx.x;
    if (e < N_EDGES) atomicAdd(&deg[ei[N_EDGES + e]], 1);
}

__global__ __launch_bounds__(256) void scan1_kernel(const int* __restrict__ deg,
                                                    int* __restrict__ offs,
                                                    int* __restrict__ blocksums) {
    __shared__ int s[SCAN_CHUNK];
    int base = blockIdx.x * SCAN_CHUNK;
    int t = threadIdx.x;
    int i0 = t, i1 = t + 256;
    int g0 = base + i0, g1 = base + i1;
    int o0 = (g0 < N_NODES) ? deg[g0] : 0;
    int o1 = (g1 < N_NODES) ? deg[g1] : 0;
    s[i0] = o0;
    s[i1] = o1;
    __syncthreads();
    for (int off = 1; off < SCAN_CHUNK; off <<= 1) {
        int v0 = (i0 >= off) ? s[i0 - off] : 0;
        int v1 = (i1 >= off) ? s[i1 - off] : 0;
        __syncthreads();
        s[i0] += v0;
        s[i1] += v1;
        __syncthreads();
    }
    if (g0 < N_NODES) offs[g0] = s[i0] - o0;
    if (g1 < N_NODES) offs[g1] = s[i1] - o1;
    if (t == 0) blocksums[blockIdx.x] = s[SCAN_CHUNK - 1];
}

__global__ __launch_bounds__(256) void scan2_kernel(int* __restrict__ blocksums) {
    __shared__ int s[256];
    int t = threadIdx.x;
    int o = (t < N_CHUNKS) ? blocksums[t] : 0;
    s[t] = o;
    __syncthreads();
    for (int off = 1; off < 256; off <<= 1) {
        int v = (t >= off) ? s[t - off] : 0;
        __syncthreads();
        s[t] += v;
        __syncthreads();
    }
    if (t < N_CHUNKS) blocksums[t] = s[t] - o;
}

__global__ __launch_bounds__(256) void scan3_kernel(int* __restrict__ offs,
                                                    const int* __restrict__ blocksums,
                                                    int* __restrict__ cursor) {
    int g = blockIdx.x * 256 + threadIdx.x;
    if (g < N_NODES) {
        int v = offs[g] + blocksums[g / SCAN_CHUNK];
        offs[g] = v;
        cursor[g] = v;
    }
    if (g == 0) offs[N_NODES] = N_EDGES;
}

__global__ __launch_bounds__(256) void fill_kernel(const int* __restrict__ ei,
                                                   int* __restrict__ cursor,
                                                   int* __restrict__ csr_src) {
    int e = blockIdx.x * 256 + threadIdx.x;
    if (e < N_EDGES) {
        int src = ei[e];
        int dst = ei[N_EDGES + e];
        int pos = atomicAdd(&cursor[dst], 1);
        csr_src[pos] = src;
    }
}

// ---- gather with fused BN+relu on the INPUT (params computed inline) --------
__global__ __launch_bounds__(256) void gather_kernel(
    const int* __restrict__ offs, const int* __restrict__ csr_src,
    const u16* __restrict__ zin, u16* __restrict__ zout,
    const float* __restrict__ eps, int layer,
    const float* __restrict__ sums, const float* __restrict__ sumsq,
    const float* __restrict__ gammas, const float* __restrict__ betas,
    int useBN) {
    int wave = threadIdx.x >> 6;
    int lane = threadIdx.x & 63;
    int node = blockIdx.x * 4 + wave;
    if (node >= N_NODES) return;
    float s = 1.0f + eps[layer];
    int c0 = lane * 4;
    float4 sc = make_float4(1.f, 1.f, 1.f, 1.f);
    float4 sh = make_float4(0.f, 0.f, 0.f, 0.f);
    if (useBN) {
        bn_params(sums, sumsq, gammas, betas, c0 + 0, sc.x, sh.x);
        bn_params(sums, sumsq, gammas, betas, c0 + 1, sc.y, sh.y);
        bn_params(sums, sumsq, gammas, betas, c0 + 2, sc.z, sh.z);
        bn_params(sums, sumsq, gammas, betas, c0 + 3, sc.w, sh.w);
    }
    int beg = offs[node], end = offs[node + 1];
    float acc[4];
    {
        ushortx4 hi = *(const ushortx4*)&zin[(size_t)node * 512 + c0];
        ushortx4 lo = *(const ushortx4*)&zin[(size_t)node * 512 + 256 + c0];
        acc[0] = uf(hi[0]) + uf(lo[0]);
        acc[1] = uf(hi[1]) + uf(lo[1]);
        acc[2] = uf(hi[2]) + uf(lo[2]);
        acc[3] = uf(hi[3]) + uf(lo[3]);
    }
    if (useBN) {
        acc[0] = fmaxf(acc[0] * sc.x + sh.x, 0.f);
        acc[1] = fmaxf(acc[1] * sc.y + sh.y, 0.f);
        acc[2] = fmaxf(acc[2] * sc.z + sh.z, 0.f);
        acc[3] = fmaxf(acc[3] * sc.w + sh.w, 0.f);
    }
    acc[0] *= s; acc[1] *= s; acc[2] *= s; acc[3] *= s;
    for (int e = beg; e < end; e++) {
        int src = csr_src[e];
        ushortx4 hi = *(const ushortx4*)&zin[(size_t)src * 512 + c0];
        ushortx4 lo = *(const ushortx4*)&zin[(size_t)src * 512 + 256 + c0];
        float v0 = uf(hi[0]) + uf(lo[0]);
        float v1 = uf(hi[1]) + uf(lo[1]);
        float v2 = uf(hi[2]) + uf(lo[2]);
        float v3 = uf(hi[3]) + uf(lo[3]);
        if (useBN) {
            v0 = fmaxf(v0 * sc.x + sh.x, 0.f);
            v1 = fmaxf(v1 * sc.y + sh.y, 0.f);
            v2 = fmaxf(v2 * sc.z + sh.z, 0.f);
            v3 = fmaxf(v3 * sc.w + sh.w, 0.f);
        }
        acc[0] += v0; acc[1] += v1; acc[2] += v2; acc[3] += v3;
    }
    ushortx4 ho, lo2;
#pragma unroll
    for (int e = 0; e < 4; e++) {
        unsigned short hb, lb;
        split_bf16(acc[e], hb, lb);
        ho[e] = hb;
        lo2[e] = lb;
    }
    *(ushortx4*)&zout[(size_t)node * 512 + c0] = ho;
    *(ushortx4*)&zout[(size_t)node * 512 + 256 + c0] = lo2;
}

// ---------------- weight packing: fragment-order bf16 hi/lo ------------------
__global__ __launch_bounds__(256) void packW_kernel(const float* __restrict__ W1s,
                                                    const float* __restrict__ W2s,
                                                    short8* __restrict__ Wpk8) {
    int id = blockIdx.x * 256 + threadIdx.x;  // < 81920
    int lane = id & 63;
    int fid = (id >> 6) & 127;
    int w = id >> 13;  // 0..9
    int kt = fid >> 4, nt = fid & 15;
    const float* Wsrc = (w < 5) ? W1s + (size_t)w * HID * HID
                                : W2s + (size_t)(w - 5) * HID * HID;
    int k0 = kt * 32 + ((lane >> 4) << 3);
    int n = nt * 16 + (lane & 15);
    short8 hi, lo;
#pragma unroll
    for (int e = 0; e < 8; e++) {
        float v = Wsrc[(size_t)(k0 + e) * HID + n];
        unsigned short hb, lb;
        split_bf16(v, hb, lb);
        hi[e] = (short)hb;
        lo[e] = (short)lb;
    }
    size_t base = (size_t)w * 16384;
    Wpk8[base + (size_t)((0 * 8 + kt) * 16 + nt) * 64 + lane] = hi;
    Wpk8[base + (size_t)((1 * 8 + kt) * 16 + nt) * 64 + lane] = lo;
}

// ---------------- fused MLP: C = (relu(A@W1+b1))@W2 + b2, + BN stats ---------
// BM=64, 4 waves; wave w owns output cols w*64..+63 in BOTH stages.
// LDS = 64 KB, temporal reuse. Phase structure (5 barriers total):
//   P0: async-stage ALL 64 A-frags (64KB, 16 issues/wave)      | barrier
//   P1: stage-1 K-loop, fully unrolled, barrier-free            | barrier
//   P2: handoff H = relu(acc+b1) -> A-frag split LDS (64KB)     | barrier
//   P3: stage-2 K-loop, barrier-free                            | barrier
//   P4: stats + cf transpose (64KB) + coalesced split writes    | barrier mid
__global__ __launch_bounds__(256, 2) void fused_mlp_kernel(
    const u16* __restrict__ A, const short8* __restrict__ W1m,
    const float* __restrict__ b1, const short8* __restrict__ W2m,
    const float* __restrict__ b2, u16* __restrict__ C, int M,
    float* __restrict__ sums, float* __restrict__ sumsq) {
    __shared__ char lds[65536];
    short8* Zf8 = (short8*)lds;  // P0/P1: 64 frags x 1KB
    u16* Hf = (u16*)lds;         // P2/P3
    float* cf = (float*)lds;     // P4
    int t = threadIdx.x;
    int lane = t & 63;
    int w = t >> 6;
    int m0 = blockIdx.x * 64;
    int col15 = lane & 15;
    int rgrp = lane >> 4;

    // ---------------- P0: async-stage all A fragments ----------------------
#pragma unroll
    for (int q = 0; q < 16; q++) {
        int f = q * 4 + w;  // 0..63: p = f>>5, ki = (f>>3)&3, ktl = (f>>2)&1, mt = f&3
        int p = f >> 5;
        int ki = (f >> 3) & 3;
        int ktl = (f >> 2) & 1;
        int mt = f & 3;
        const u16* src = &A[(size_t)(m0 + mt * 16 + col15) * 512 + p * 256 +
                            ki * 64 + ktl * 32 + (rgrp << 3)];
        load16_to_lds(src, &Zf8[f * 64]);
    }
    __syncthreads();

    // ---------------- P1: acc = Z @ W1 (barrier-free) ----------------------
    floatx4 acc[4][4];
#pragma unroll
    for (int i = 0; i < 4; i++)
#pragma unroll
        for (int j = 0; j < 4; j++) acc[i][j] = (floatx4)0.0f;

#pragma unroll
    for (int kk = 0; kk < 8; kk++) {  // kk = ki*2 + ktl
        int ki = kk >> 1, ktl = kk & 1;
        short8 bb0[4], bb1[4];
#pragma unroll
        for (int j = 0; j < 4; j++) {
            bb0[j] = W1m[((size_t)(0 * 8 + kk) * 16 + (w * 4 + j)) * 64 + lane];
            bb1[j] = W1m[((size_t)(1 * 8 + kk) * 16 + (w * 4 + j)) * 64 + lane];
        }
        short8 ah[4], al[4];
#pragma unroll
        for (int mt = 0; mt < 4; mt++) {
            ah[mt] = Zf8[((0 << 5) + ki * 8 + ktl * 4 + mt) * 64 + lane];
            al[mt] = Zf8[((1 << 5) + ki * 8 + ktl * 4 + mt) * 64 + lane];
        }
#pragma unroll
        for (int i = 0; i < 4; i++)
#pragma unroll
            for (int j = 0; j < 4; j++) {
                acc[i][j] = __builtin_amdgcn_mfma_f32_16x16x32_bf16(
                    ah[i], bb0[j], acc[i][j], 0, 0, 0);
                acc[i][j] = __builtin_amdgcn_mfma_f32_16x16x32_bf16(
                    ah[i], bb1[j], acc[i][j], 0, 0, 0);
                acc[i][j] = __builtin_amdgcn_mfma_f32_16x16x32_bf16(
                    al[i], bb0[j], acc[i][j], 0, 0, 0);
            }
    }
    __syncthreads();  // Zf dead; Hf takes over

    // ---------------- P2: H = relu(acc + b1) -> A-frag split LDS -----------
#pragma unroll
    for (int j = 0; j < 4; j++) {
        int col = w * 64 + j * 16 + col15;
        float bv = b1[col];
        int kt2 = col >> 5;
        int colg = (col & 31) >> 3;
        int e = col & 7;
#pragma unroll
        for (int i = 0; i < 4; i++) {
            int lane_a = rgrp * 4 + colg * 16;
#pragma unroll
            for (int r = 0; r < 4; r++) {
                float v = fmaxf(acc[i][j][r] + bv, 0.0f);
                unsigned short hb, lb;
                split_bf16(v, hb, lb);
                Hf[(((0 * 8 + kt2) * 4 + i) * 64 + lane_a + r) * 8 + e] = hb;
                Hf[(((1 * 8 + kt2) * 4 + i) * 64 + lane_a + r) * 8 + e] = lb;
            }
        }
    }
    __syncthreads();

    // ---------------- P3: acc2 = H @ W2 (barrier-free) ---------------------
    floatx4 acc2[4][4];
#pragma unroll
    for (int i = 0; i < 4; i++)
#pragma unroll
        for (int j = 0; j < 4; j++) acc2[i][j] = (floatx4)0.0f;

#pragma unroll
    for (int kj = 0; kj < 8; kj++) {
        short8 bb2[2][4];
#pragma unroll
        for (int p = 0; p < 2; p++)
#pragma unroll
            for (int j = 0; j < 4; j++)
                bb2[p][j] =
                    W2m[((size_t)(p * 8 + kj) * 16 + (w * 4 + j)) * 64 + lane];
        short8 ah2[4], al2[4];
#pragma unroll
        for (int mt = 0; mt < 4; mt++) {
            ah2[mt] = *(short8*)&Hf[(((0 * 8 + kj) * 4 + mt) * 64 + lane) * 8];
            al2[mt] = *(short8*)&Hf[(((1 * 8 + kj) * 4 + mt) * 64 + lane) * 8];
        }
#pragma unroll
        for (int i = 0; i < 4; i++)
#pragma unroll
            for (int j = 0; j < 4; j++) {
                acc2[i][j] = __builtin_amdgcn_mfma_f32_16x16x32_bf16(
                    ah2[i], bb2[0][j], acc2[i][j], 0, 0, 0);
                acc2[i][j] = __builtin_amdgcn_mfma_f32_16x16x32_bf16(
                    ah2[i], bb2[1][j], acc2[i][j], 0, 0, 0);
                acc2[i][j] = __builtin_amdgcn_mfma_f32_16x16x32_bf16(
                    al2[i], bb2[0][j], acc2[i][j], 0, 0, 0);
            }
    }
    __syncthreads();  // Hf dead; cf takes over

    // ---------------- P4: stats + LDS transpose + split write --------------
#pragma unroll
    for (int j = 0; j < 4; j++) {
        int col = w * 64 + j * 16 + col15;
        float bv = b2[col];
        float csum = 0.f, csq = 0.f;
#pragma unroll
        for (int i = 0; i < 4; i++) {
            int rowb = i * 16 + rgrp * 4;
#pragma unroll
            for (int r = 0; r < 4; r++) {
                float v = acc2[i][j][r] + bv;
                cf[(rowb + r) * 256 + col] = v;
                if (m0 + rowb + r < M) {
                    csum += v;
                    csq += v * v;
                }
            }
        }
        csum += __shfl_xor(csum, 16);
        csum += __shfl_xor(csum, 32);
        csq += __shfl_xor(csq, 16);
        csq += __shfl_xor(csq, 32);
        if (rgrp == 0) {
            atomicAdd(&sums[col], csum);
            atomicAdd(&sumsq[col], csq);
        }
    }
    __syncthreads();
#pragma unroll
    for (int k = 0; k < 16; k++) {
        int fi = (k * 256 + t) * 4;  // flat float idx in 64x256 tile
        int row = fi >> 8, colc = fi & 255;
        int m = m0 + row;
        if (m >= M) continue;
        float4 v4 = *(float4*)&cf[fi];
        ushortx4 h4, l4;
        unsigned short hb, lb;
        split_bf16(v4.x, hb, lb); h4[0] = hb; l4[0] = lb;
        split_bf16(v4.y, hb, lb); h4[1] = hb; l4[1] = lb;
        split_bf16(v4.z, hb, lb); h4[2] = hb; l4[2] = lb;
        split_bf16(v4.w, hb, lb); h4[3] = hb; l4[3] = lb;
        *(ushortx4*)&C[(size_t)m * 512 + colc] = h4;
        *(ushortx4*)&C[(size_t)m * 512 + 256 + colc] = l4;
    }
}

// ---------------- pooling (batch sorted), fused final BN+relu ----------------
__global__ __launch_bounds__(256) void bounds_kernel(const int* __restrict__ batch,
                                                     int* __restrict__ start) {
    int g = blockIdx.x * 256 + threadIdx.x;
    if (g > N_GRAPHS) return;
    int lo = 0, hi = N_NODES;
    while (lo < hi) {
        int mid = (lo + hi) >> 1;
        if (batch[mid] < g) lo = mid + 1;
        else hi = mid;
    }
    start[g] = lo;
}

__global__ __launch_bounds__(256) void segpool_kernel(
    const u16* __restrict__ z, const int* __restrict__ start,
    const float* __restrict__ sums, const float* __restrict__ sumsq,
    const float* __restrict__ gammas, const float* __restrict__ betas,
    float* __restrict__ pooled) {
    int g = blockIdx.x;
    int c = threadIdx.x;
    float sc, sh;
    bn_params(sums, sumsq, gammas, betas, c, sc, sh);
    int beg = start[g], end = start[g + 1];
    float s = 0.f;
    for (int n = beg; n < end; n++) {
        float v = uf(z[(size_t)n * 512 + c]) + uf(z[(size_t)n * 512 + 256 + c]);
        s += fmaxf(v * sc + sh, 0.f);
    }
    float inv = 1.0f / fmaxf((float)(end - beg), 1.0f);
    pooled[(size_t)g * HID + c] = s * inv;
}

// ---------------- readout ----------------------------------------------------
__global__ __launch_bounds__(256) void readout_kernel(
    const float* __restrict__ pooled, const float* __restrict__ Wr1,
    const float* __restrict__ br1, const float* __restrict__ Wr2,
    const float* __restrict__ br2, float* __restrict__ out) {
    __shared__ float p[HID];
    __shared__ float red[4];
    int g = blockIdx.x;
    int c = threadIdx.x;
    p[c] = pooled[(size_t)g * HID + c];
    __syncthreads();
    float acc = br1[c];
    for (int k = 0; k < HID; k++) acc += p[k] * Wr1[k * HID + c];
    acc = fmaxf(acc, 0.f);
    float v = acc * Wr2[c];
#pragma unroll
    for (int off = 32; off > 0; off >>= 1) v += __shfl_down(v, off, 64);
    if ((c & 63) == 0) red[c >> 6] = v;
    __syncthreads();
    if (c == 0) out[g] = red[0] + red[1] + red[2] + red[3] + br2[0];
}

extern "C" void kernel_launch(void* const* d_in, const int* in_sizes, int n_in,
                              void* d_out, int out_size, void* d_ws, size_t ws_size,
                              hipStream_t stream) {
    const float* x      = (const float*)d_in[0];
    const int*   ei     = (const int*)d_in[1];
    const int*   batch  = (const int*)d_in[2];
    const float* Wp     = (const float*)d_in[3];
    const float* bp     = (const float*)d_in[4];
    const float* eps    = (const float*)d_in[5];
    const float* W1s    = (const float*)d_in[6];
    const float* b1s    = (const float*)d_in[7];
    const float* W2s    = (const float*)d_in[8];
    const float* b2s    = (const float*)d_in[9];
    const float* gammas = (const float*)d_in[10];
    const float* betas  = (const float*)d_in[11];
    const float* Wr1    = (const float*)d_in[12];
    const float* br1    = (const float*)d_in[13];
    const float* Wr2    = (const float*)d_in[14];
    const float* br2    = (const float*)d_in[15];
    float* out = (float*)d_out;

    const size_t ROWS = (size_t)N_NODES + ROW_PAD;
    u16* bufA     = (u16*)d_ws;                  // ROWS*512 u16  (z buffer)
    u16* bufB     = bufA + ROWS * 512;           // gather scratch
    short8* Wpk8  = (short8*)(bufB + ROWS * 512);  // 10*16384 short8 = 2.62 MB
    float* sums   = (float*)(Wpk8 + 10 * 16384);   // LAYERS*512 (sum|sumsq)
    float* pooled = sums + LAYERS * 512;
    int* start     = (int*)(pooled + (size_t)N_GRAPHS * HID);  // N_GRAPHS+1
    int* deg       = start + N_GRAPHS + 1;
    int* offs      = deg + N_NODES;        // N_NODES+1
    int* cursor    = offs + N_NODES + 1;
    int* csr_src   = cursor + N_NODES;
    int* blocksums = csr_src + N_EDGES;    // N_CHUNKS

    // ---- CSR build + weight packing + zeroing (once per launch) ----
    hipMemsetAsync(deg, 0, N_NODES * sizeof(int), stream);
    hipMemsetAsync(sums, 0, LAYERS * 512 * sizeof(float), stream);
    hist_kernel<<<(N_EDGES + 255) / 256, 256, 0, stream>>>(ei, deg);
    scan1_kernel<<<N_CHUNKS, 256, 0, stream>>>(deg, offs, blocksums);
    scan2_kernel<<<1, 256, 0, stream>>>(blocksums);
    scan3_kernel<<<(N_NODES + 255) / 256, 256, 0, stream>>>(offs, blocksums,
                                                            cursor);
    fill_kernel<<<(N_EDGES + 255) / 256, 256, 0, stream>>>(ei, cursor, csr_src);
    packW_kernel<<<320, 256, 0, stream>>>(W1s, W2s, Wpk8);
    bounds_kernel<<<(N_GRAPHS + 1 + 255) / 256, 256, 0, stream>>>(batch, start);

    // h0 = x @ Wp + bp  -> bufA (split bf16)
    proj_kernel<<<(N_NODES + PROJ_CH - 1) / PROJ_CH, 256, 0, stream>>>(x, Wp, bp,
                                                                       bufA);

    // Invariant: bufA always holds current z (pre-BN); bufB is gather scratch.
    const int MLP_BLOCKS = (N_NODES + 63) / 64;  // 1563
    for (int l = 0; l < LAYERS; l++) {
        float* lsums = sums + l * 512;
        float* lsumsq = lsums + 256;
        const float* psums = sums + (l - 1) * 512;  // valid only for l>0
        // B = (1+eps)*f(A) + sum f(A[src]);  f = BN(l-1)+relu for l>0
        gather_kernel<<<(N_NODES + 3) / 4, 256, 0, stream>>>(
            offs, csr_src, bufA, bufB, eps, l,
            l > 0 ? psums : sums, l > 0 ? psums + 256 : sums,
            gammas + (l > 0 ? (l - 1) : 0) * HID,
            betas + (l > 0 ? (l - 1) : 0) * HID, l > 0 ? 1 : 0);
        // A = (relu(B @ W1 + b1)) @ W2 + b2, fused, + column stats
        fused_mlp_kernel<<<MLP_BLOCKS, 256, 0, stream>>>(
            bufB, Wpk8 + (size_t)l * 16384, b1s + l * HID,
            Wpk8 + (size_t)(5 + l) * 16384, b2s + l * HID, bufA, N_NODES,
            lsums, lsumsq);
    }

    // bufA holds z4 (pre-BN); segpool applies BN(4)+relu inline
    segpool_kernel<<<N_GRAPHS, 256, 0, stream>>>(
        bufA, start, sums + 4 * 512, sums + 4 * 512 + 256, gammas + 4 * HID,
        betas + 4 * HID, pooled);
    readout_kernel<<<N_GRAPHS, 256, 0, stream>>>(pooled, Wr1, br1, Wr2, br2, out);
}

// Round 14
// 1071.810 us; speedup vs baseline: 1.3087x; 1.0352x over previous
//
#include <hip/hip_runtime.h>

#define N_NODES 100000
#define N_EDGES 300000
#define N_GRAPHS 2048
#define IN_DIM 38
#define HID 256
#define LAYERS 5
#define BN_EPS 1e-5f

#define SCAN_CHUNK 512
#define N_CHUNKS ((N_NODES + SCAN_CHUNK - 1) / SCAN_CHUNK)  // 196

// z-buffer (layer output) layout: INTERLEAVED u32 per channel:
//   word = hi_bf16 | (lo_bf16 << 16), row = 256 u32 = 1 KB.
// gather-output / GEMM-A layout: SPLIT planes, row = 512 u16:
//   [m*512 + c] = hi, [m*512 + 256 + c] = lo.
#define ROW_PAD 128

typedef unsigned short u16;
typedef unsigned int u32;
typedef __attribute__((ext_vector_type(8))) short short8;       // 8 bf16 = 4 VGPR
typedef __attribute__((ext_vector_type(4))) unsigned short ushortx4;
typedef __attribute__((ext_vector_type(4))) unsigned int uintx4;
typedef __attribute__((ext_vector_type(4))) float floatx4;      // MFMA acc

__device__ __forceinline__ unsigned short bf16_rne(float f) {
    unsigned int u = __float_as_uint(f);
    unsigned int r = (u + 0x7fffu + ((u >> 16) & 1u)) >> 16;
    return (unsigned short)r;
}
__device__ __forceinline__ float uf(unsigned short b) {
    return __uint_as_float((unsigned int)b << 16);
}
__device__ __forceinline__ float unpack_pair(u32 w) {  // hi|lo<<16 -> value
    return uf((unsigned short)(w & 0xffffu)) + uf((unsigned short)(w >> 16));
}
__device__ __forceinline__ void split_bf16(float v, unsigned short& hi,
                                           unsigned short& lo) {
    hi = bf16_rne(v);
    float hf = __uint_as_float((unsigned int)hi << 16);
    lo = (unsigned short)(__float_as_uint(v - hf) >> 16);  // truncated residual
}
__device__ __forceinline__ u32 pack_pair(float v) {
    unsigned short hb, lb;
    split_bf16(v, hb, lb);
    return (u32)hb | ((u32)lb << 16);
}
// async 16B global -> LDS (HW dest = wave-uniform base + lane*16)
__device__ __forceinline__ void load16_to_lds(const void* g, void* l) {
    __builtin_amdgcn_global_load_lds(
        (const __attribute__((address_space(1))) unsigned int*)g,
        (__attribute__((address_space(3))) unsigned int*)l, 16, 0, 0);
}
// BN scale/shift for channel c from per-layer sums/sumsq
__device__ __forceinline__ void bn_params(const float* sums, const float* sumsq,
                                          const float* gammas,
                                          const float* betas, int c, float& sc,
                                          float& sh) {
    const float invN = 1.0f / (float)N_NODES;
    float mu = sums[c] * invN;
    float var = sumsq[c] * invN - mu * mu;
    float rs = rsqrtf(var + BN_EPS);
    float g = gammas[c];
    sc = rs * g;
    sh = betas[c] - mu * rs * g;
}

// ---------------- projection: h = x @ Wp + bp  ([N,38]@[38,256]) -------------
#define PROJ_CH 64
__global__ __launch_bounds__(256) void proj_kernel(
    const float* __restrict__ x, const float* __restrict__ Wp,
    const float* __restrict__ bp, u32* __restrict__ h) {
    __shared__ float xs[PROJ_CH * IN_DIM];
    int t = threadIdx.x;
    float w[IN_DIM];
#pragma unroll
    for (int k = 0; k < IN_DIM; k++) w[k] = Wp[k * HID + t];
    float b = bp[t];
    int n0 = blockIdx.x * PROJ_CH;
    int count = min(PROJ_CH, N_NODES - n0);
    int total = count * IN_DIM;
    const float* xbase = x + (size_t)n0 * IN_DIM;
    for (int i = t; i < total; i += 256) xs[i] = xbase[i];
    __syncthreads();
    for (int n = 0; n < count; n++) {
        float acc = b;
        const float* xr = &xs[n * IN_DIM];
#pragma unroll
        for (int k = 0; k < IN_DIM; k++) acc = fmaf(xr[k], w[k], acc);
        h[(size_t)(n0 + n) * 256 + t] = pack_pair(acc);
    }
}

// ---------------- CSR build --------------------------------------------------
__global__ __launch_bounds__(256) void hist_kernel(const int* __restrict__ ei,
                                                   int* __restrict__ deg) {
    int e = blockIdx.x * 256 + threadIdx.x;
    if (e < N_EDGES) atomicAdd(&deg[ei[N_EDGES + e]], 1);
}

__global__ __launch_bounds__(256) void scan1_kernel(const int* __restrict__ deg,
                                                    int* __restrict__ offs,
                                                    int* __restrict__ blocksums) {
    __shared__ int s[SCAN_CHUNK];
    int base = blockIdx.x * SCAN_CHUNK;
    int t = threadIdx.x;
    int i0 = t, i1 = t + 256;
    int g0 = base + i0, g1 = base + i1;
    int o0 = (g0 < N_NODES) ? deg[g0] : 0;
    int o1 = (g1 < N_NODES) ? deg[g1] : 0;
    s[i0] = o0;
    s[i1] = o1;
    __syncthreads();
    for (int off = 1; off < SCAN_CHUNK; off <<= 1) {
        int v0 = (i0 >= off) ? s[i0 - off] : 0;
        int v1 = (i1 >= off) ? s[i1 - off] : 0;
        __syncthreads();
        s[i0] += v0;
        s[i1] += v1;
        __syncthreads();
    }
    if (g0 < N_NODES) offs[g0] = s[i0] - o0;
    if (g1 < N_NODES) offs[g1] = s[i1] - o1;
    if (t == 0) blocksums[blockIdx.x] = s[SCAN_CHUNK - 1];
}

__global__ __launch_bounds__(256) void scan2_kernel(int* __restrict__ blocksums) {
    __shared__ int s[256];
    int t = threadIdx.x;
    int o = (t < N_CHUNKS) ? blocksums[t] : 0;
    s[t] = o;
    __syncthreads();
    for (int off = 1; off < 256; off <<= 1) {
        int v = (t >= off) ? s[t - off] : 0;
        __syncthreads();
        s[t] += v;
        __syncthreads();
    }
    if (t < N_CHUNKS) blocksums[t] = s[t] - o;
}

__global__ __launch_bounds__(256) void scan3_kernel(int* __restrict__ offs,
                                                    const int* __restrict__ blocksums,
                                                    int* __restrict__ cursor) {
    int g = blockIdx.x * 256 + threadIdx.x;
    if (g < N_NODES) {
        int v = offs[g] + blocksums[g / SCAN_CHUNK];
        offs[g] = v;
        cursor[g] = v;
    }
    if (g == 0) offs[N_NODES] = N_EDGES;
}

__global__ __launch_bounds__(256) void fill_kernel(const int* __restrict__ ei,
                                                   int* __restrict__ cursor,
                                                   int* __restrict__ csr_src) {
    int e = blockIdx.x * 256 + threadIdx.x;
    if (e < N_EDGES) {
        int src = ei[e];
        int dst = ei[N_EDGES + e];
        int pos = atomicAdd(&cursor[dst], 1);
        csr_src[pos] = src;
    }
}

// ---- gather: interleaved z in, split-plane out; BN+relu fused on input ------
__global__ __launch_bounds__(256) void gather_kernel(
    const int* __restrict__ offs, const int* __restrict__ csr_src,
    const u32* __restrict__ zin, u16* __restrict__ zout,
    const float* __restrict__ eps, int layer,
    const float* __restrict__ sums, const float* __restrict__ sumsq,
    const float* __restrict__ gammas, const float* __restrict__ betas,
    int useBN) {
    int wave = threadIdx.x >> 6;
    int lane = threadIdx.x & 63;
    int node = blockIdx.x * 4 + wave;
    if (node >= N_NODES) return;
    float s = 1.0f + eps[layer];
    int c0 = lane * 4;
    float4 sc = make_float4(1.f, 1.f, 1.f, 1.f);
    float4 sh = make_float4(0.f, 0.f, 0.f, 0.f);
    if (useBN) {
        bn_params(sums, sumsq, gammas, betas, c0 + 0, sc.x, sh.x);
        bn_params(sums, sumsq, gammas, betas, c0 + 1, sc.y, sh.y);
        bn_params(sums, sumsq, gammas, betas, c0 + 2, sc.z, sh.z);
        bn_params(sums, sumsq, gammas, betas, c0 + 3, sc.w, sh.w);
    }
    int beg = offs[node], end = offs[node + 1];
    float acc[4];
    {
        uintx4 v4 = *(const uintx4*)&zin[(size_t)node * 256 + c0];
        acc[0] = unpack_pair(v4[0]);
        acc[1] = unpack_pair(v4[1]);
        acc[2] = unpack_pair(v4[2]);
        acc[3] = unpack_pair(v4[3]);
    }
    if (useBN) {
        acc[0] = fmaxf(acc[0] * sc.x + sh.x, 0.f);
        acc[1] = fmaxf(acc[1] * sc.y + sh.y, 0.f);
        acc[2] = fmaxf(acc[2] * sc.z + sh.z, 0.f);
        acc[3] = fmaxf(acc[3] * sc.w + sh.w, 0.f);
    }
    acc[0] *= s; acc[1] *= s; acc[2] *= s; acc[3] *= s;
    int e = beg;
    int srcN = (e < end) ? csr_src[e] : 0;
    for (; e < end; e++) {
        int src = srcN;
        if (e + 1 < end) srcN = csr_src[e + 1];  // prefetch next index
        uintx4 v4 = *(const uintx4*)&zin[(size_t)src * 256 + c0];
        float v0 = unpack_pair(v4[0]);
        float v1 = unpack_pair(v4[1]);
        float v2 = unpack_pair(v4[2]);
        float v3 = unpack_pair(v4[3]);
        if (useBN) {
            v0 = fmaxf(v0 * sc.x + sh.x, 0.f);
            v1 = fmaxf(v1 * sc.y + sh.y, 0.f);
            v2 = fmaxf(v2 * sc.z + sh.z, 0.f);
            v3 = fmaxf(v3 * sc.w + sh.w, 0.f);
        }
        acc[0] += v0; acc[1] += v1; acc[2] += v2; acc[3] += v3;
    }
    ushortx4 ho, lo2;
#pragma unroll
    for (int q = 0; q < 4; q++) {
        unsigned short hb, lb;
        split_bf16(acc[q], hb, lb);
        ho[q] = hb;
        lo2[q] = lb;
    }
    *(ushortx4*)&zout[(size_t)node * 512 + c0] = ho;
    *(ushortx4*)&zout[(size_t)node * 512 + 256 + c0] = lo2;
}

// ---------------- weight packing: fragment-order bf16 hi/lo ------------------
__global__ __launch_bounds__(256) void packW_kernel(const float* __restrict__ W1s,
                                                    const float* __restrict__ W2s,
                                                    short8* __restrict__ Wpk8) {
    int id = blockIdx.x * 256 + threadIdx.x;  // < 81920
    int lane = id & 63;
    int fid = (id >> 6) & 127;
    int w = id >> 13;  // 0..9
    int kt = fid >> 4, nt = fid & 15;
    const float* Wsrc = (w < 5) ? W1s + (size_t)w * HID * HID
                                : W2s + (size_t)(w - 5) * HID * HID;
    int k0 = kt * 32 + ((lane >> 4) << 3);
    int n = nt * 16 + (lane & 15);
    short8 hi, lo;
#pragma unroll
    for (int e = 0; e < 8; e++) {
        float v = Wsrc[(size_t)(k0 + e) * HID + n];
        unsigned short hb, lb;
        split_bf16(v, hb, lb);
        hi[e] = (short)hb;
        lo[e] = (short)lb;
    }
    size_t base = (size_t)w * 16384;
    Wpk8[base + (size_t)((0 * 8 + kt) * 16 + nt) * 64 + lane] = hi;
    Wpk8[base + (size_t)((1 * 8 + kt) * 16 + nt) * 64 + lane] = lo;
}

// ---------------- fused MLP: C = (relu(A@W1+b1))@W2 + b2, + BN stats ---------
// A: split-plane (gather output). C: interleaved z. LDS 64 KB temporal reuse.
__global__ __launch_bounds__(256, 2) void fused_mlp_kernel(
    const u16* __restrict__ A, const short8* __restrict__ W1m,
    const float* __restrict__ b1, const short8* __restrict__ W2m,
    const float* __restrict__ b2, u32* __restrict__ C, int M,
    float* __restrict__ sums, float* __restrict__ sumsq) {
    __shared__ char lds[65536];
    short8* Zf8 = (short8*)lds;  // P0/P1: 64 frags x 1KB
    u16* Hf = (u16*)lds;         // P2/P3
    float* cf = (float*)lds;     // P4
    int t = threadIdx.x;
    int lane = t & 63;
    int w = t >> 6;
    int m0 = blockIdx.x * 64;
    int col15 = lane & 15;
    int rgrp = lane >> 4;

    // ---------------- P0: async-stage all A fragments ----------------------
#pragma unroll
    for (int q = 0; q < 16; q++) {
        int f = q * 4 + w;  // p = f>>5, ki = (f>>3)&3, ktl = (f>>2)&1, mt = f&3
        int p = f >> 5;
        int ki = (f >> 3) & 3;
        int ktl = (f >> 2) & 1;
        int mt = f & 3;
        const u16* src = &A[(size_t)(m0 + mt * 16 + col15) * 512 + p * 256 +
                            ki * 64 + ktl * 32 + (rgrp << 3)];
        load16_to_lds(src, &Zf8[f * 64]);
    }
    __syncthreads();

    // ---------------- P1: acc = Z @ W1 (barrier-free) ----------------------
    floatx4 acc[4][4];
#pragma unroll
    for (int i = 0; i < 4; i++)
#pragma unroll
        for (int j = 0; j < 4; j++) acc[i][j] = (floatx4)0.0f;

#pragma unroll
    for (int kk = 0; kk < 8; kk++) {
        int ki = kk >> 1, ktl = kk & 1;
        short8 bb0[4], bb1[4];
#pragma unroll
        for (int j = 0; j < 4; j++) {
            bb0[j] = W1m[((size_t)(0 * 8 + kk) * 16 + (w * 4 + j)) * 64 + lane];
            bb1[j] = W1m[((size_t)(1 * 8 + kk) * 16 + (w * 4 + j)) * 64 + lane];
        }
        short8 ah[4], al[4];
#pragma unroll
        for (int mt = 0; mt < 4; mt++) {
            ah[mt] = Zf8[((0 << 5) + ki * 8 + ktl * 4 + mt) * 64 + lane];
            al[mt] = Zf8[((1 << 5) + ki * 8 + ktl * 4 + mt) * 64 + lane];
        }
#pragma unroll
        for (int i = 0; i < 4; i++)
#pragma unroll
            for (int j = 0; j < 4; j++) {
                acc[i][j] = __builtin_amdgcn_mfma_f32_16x16x32_bf16(
                    ah[i], bb0[j], acc[i][j], 0, 0, 0);
                acc[i][j] = __builtin_amdgcn_mfma_f32_16x16x32_bf16(
                    ah[i], bb1[j], acc[i][j], 0, 0, 0);
                acc[i][j] = __builtin_amdgcn_mfma_f32_16x16x32_bf16(
                    al[i], bb0[j], acc[i][j], 0, 0, 0);
            }
    }
    __syncthreads();  // Zf dead; Hf takes over

    // ---------------- P2: H = relu(acc + b1) -> A-frag split LDS -----------
#pragma unroll
    for (int j = 0; j < 4; j++) {
        int col = w * 64 + j * 16 + col15;
        float bv = b1[col];
        int kt2 = col >> 5;
        int colg = (col & 31) >> 3;
        int e = col & 7;
#pragma unroll
        for (int i = 0; i < 4; i++) {
            int lane_a = rgrp * 4 + colg * 16;
#pragma unroll
            for (int r = 0; r < 4; r++) {
                float v = fmaxf(acc[i][j][r] + bv, 0.0f);
                unsigned short hb, lb;
                split_bf16(v, hb, lb);
                Hf[(((0 * 8 + kt2) * 4 + i) * 64 + lane_a + r) * 8 + e] = hb;
                Hf[(((1 * 8 + kt2) * 4 + i) * 64 + lane_a + r) * 8 + e] = lb;
            }
        }
    }
    __syncthreads();

    // ---------------- P3: acc2 = H @ W2 (barrier-free) ---------------------
    floatx4 acc2[4][4];
#pragma unroll
    for (int i = 0; i < 4; i++)
#pragma unroll
        for (int j = 0; j < 4; j++) acc2[i][j] = (floatx4)0.0f;

#pragma unroll
    for (int kj = 0; kj < 8; kj++) {
        short8 bb2[2][4];
#pragma unroll
        for (int p = 0; p < 2; p++)
#pragma unroll
            for (int j = 0; j < 4; j++)
                bb2[p][j] =
                    W2m[((size_t)(p * 8 + kj) * 16 + (w * 4 + j)) * 64 + lane];
        short8 ah2[4], al2[4];
#pragma unroll
        for (int mt = 0; mt < 4; mt++) {
            ah2[mt] = *(short8*)&Hf[(((0 * 8 + kj) * 4 + mt) * 64 + lane) * 8];
            al2[mt] = *(short8*)&Hf[(((1 * 8 + kj) * 4 + mt) * 64 + lane) * 8];
        }
#pragma unroll
        for (int i = 0; i < 4; i++)
#pragma unroll
            for (int j = 0; j < 4; j++) {
                acc2[i][j] = __builtin_amdgcn_mfma_f32_16x16x32_bf16(
                    ah2[i], bb2[0][j], acc2[i][j], 0, 0, 0);
                acc2[i][j] = __builtin_amdgcn_mfma_f32_16x16x32_bf16(
                    ah2[i], bb2[1][j], acc2[i][j], 0, 0, 0);
                acc2[i][j] = __builtin_amdgcn_mfma_f32_16x16x32_bf16(
                    al2[i], bb2[0][j], acc2[i][j], 0, 0, 0);
            }
    }
    __syncthreads();  // Hf dead; cf takes over

    // ---------------- P4: stats + LDS transpose + interleaved write --------
#pragma unroll
    for (int j = 0; j < 4; j++) {
        int col = w * 64 + j * 16 + col15;
        float bv = b2[col];
        float csum = 0.f, csq = 0.f;
#pragma unroll
        for (int i = 0; i < 4; i++) {
            int rowb = i * 16 + rgrp * 4;
#pragma unroll
            for (int r = 0; r < 4; r++) {
                float v = acc2[i][j][r] + bv;
                cf[(rowb + r) * 256 + col] = v;
                if (m0 + rowb + r < M) {
                    csum += v;
                    csq += v * v;
                }
            }
        }
        csum += __shfl_xor(csum, 16);
        csum += __shfl_xor(csum, 32);
        csq += __shfl_xor(csq, 16);
        csq += __shfl_xor(csq, 32);
        if (rgrp == 0) {
            atomicAdd(&sums[col], csum);
            atomicAdd(&sumsq[col], csq);
        }
    }
    __syncthreads();
#pragma unroll
    for (int k = 0; k < 16; k++) {
        int fi = (k * 256 + t) * 4;  // flat float idx in 64x256 tile
        int row = fi >> 8, colc = fi & 255;
        int m = m0 + row;
        if (m >= M) continue;
        float4 v4 = *(float4*)&cf[fi];
        uintx4 o;
        o[0] = pack_pair(v4.x);
        o[1] = pack_pair(v4.y);
        o[2] = pack_pair(v4.z);
        o[3] = pack_pair(v4.w);
        *(uintx4*)&C[(size_t)m * 256 + colc] = o;
    }
}

// ---------------- pooling (batch sorted), fused final BN+relu ----------------
__global__ __launch_bounds__(256) void bounds_kernel(const int* __restrict__ batch,
                                                     int* __restrict__ start) {
    int g = blockIdx.x * 256 + threadIdx.x;
    if (g > N_GRAPHS) return;
    int lo = 0, hi = N_NODES;
    while (lo < hi) {
        int mid = (lo + hi) >> 1;
        if (batch[mid] < g) lo = mid + 1;
        else hi = mid;
    }
    start[g] = lo;
}

__global__ __launch_bounds__(256) void segpool_kernel(
    const u32* __restrict__ z, const int* __restrict__ start,
    const float* __restrict__ sums, const float* __restrict__ sumsq,
    const float* __restrict__ gammas, const float* __restrict__ betas,
    float* __restrict__ pooled) {
    int g = blockIdx.x;
    int c = threadIdx.x;
    float sc, sh;
    bn_params(sums, sumsq, gammas, betas, c, sc, sh);
    int beg = start[g], end = start[g + 1];
    float s = 0.f;
    for (int n = beg; n < end; n++) {
        float v = unpack_pair(z[(size_t)n * 256 + c]);
        s += fmaxf(v * sc + sh, 0.f);
    }
    float inv = 1.0f / fmaxf((float)(end - beg), 1.0f);
    pooled[(size_t)g * HID + c] = s * inv;
}

// ---------------- readout ----------------------------------------------------
__global__ __launch_bounds__(256) void readout_kernel(
    const float* __restrict__ pooled, const float* __restrict__ Wr1,
    const float* __restrict__ br1, const float* __restrict__ Wr2,
    const float* __restrict__ br2, float* __restrict__ out) {
    __shared__ float p[HID];
    __shared__ float red[4];
    int g = blockIdx.x;
    int c = threadIdx.x;
    p[c] = pooled[(size_t)g * HID + c];
    __syncthreads();
    float acc = br1[c];
    for (int k = 0; k < HID; k++) acc += p[k] * Wr1[k * HID + c];
    acc = fmaxf(acc, 0.f);
    float v = acc * Wr2[c];
#pragma unroll
    for (int off = 32; off > 0; off >>= 1) v += __shfl_down(v, off, 64);
    if ((c & 63) == 0) red[c >> 6] = v;
    __syncthreads();
    if (c == 0) out[g] = red[0] + red[1] + red[2] + red[3] + br2[0];
}

extern "C" void kernel_launch(void* const* d_in, const int* in_sizes, int n_in,
                              void* d_out, int out_size, void* d_ws, size_t ws_size,
                              hipStream_t stream) {
    const float* x      = (const float*)d_in[0];
    const int*   ei     = (const int*)d_in[1];
    const int*   batch  = (const int*)d_in[2];
    const float* Wp     = (const float*)d_in[3];
    const float* bp     = (const float*)d_in[4];
    const float* eps    = (const float*)d_in[5];
    const float* W1s    = (const float*)d_in[6];
    const float* b1s    = (const float*)d_in[7];
    const float* W2s    = (const float*)d_in[8];
    const float* b2s    = (const float*)d_in[9];
    const float* gammas = (const float*)d_in[10];
    const float* betas  = (const float*)d_in[11];
    const float* Wr1    = (const float*)d_in[12];
    const float* br1    = (const float*)d_in[13];
    const float* Wr2    = (const float*)d_in[14];
    const float* br2    = (const float*)d_in[15];
    float* out = (float*)d_out;

    const size_t ROWS = (size_t)N_NODES + ROW_PAD;
    u32* bufA     = (u32*)d_ws;                    // z buffer, interleaved
    u16* bufB     = (u16*)(bufA + ROWS * 256);     // gather scratch, split
    short8* Wpk8  = (short8*)(bufB + ROWS * 512);  // 10*16384 short8 = 2.62 MB
    float* sums   = (float*)(Wpk8 + 10 * 16384);   // LAYERS*512 (sum|sumsq)
    float* pooled = sums + LAYERS * 512;
    int* start     = (int*)(pooled + (size_t)N_GRAPHS * HID);  // N_GRAPHS+1
    int* deg       = start + N_GRAPHS + 1;
    int* offs      = deg + N_NODES;        // N_NODES+1
    int* cursor    = offs + N_NODES + 1;
    int* csr_src   = cursor + N_NODES;
    int* blocksums = csr_src + N_EDGES;    // N_CHUNKS

    // ---- CSR build + weight packing + zeroing (once per launch) ----
    hipMemsetAsync(deg, 0, N_NODES * sizeof(int), stream);
    hipMemsetAsync(sums, 0, LAYERS * 512 * sizeof(float), stream);
    hist_kernel<<<(N_EDGES + 255) / 256, 256, 0, stream>>>(ei, deg);
    scan1_kernel<<<N_CHUNKS, 256, 0, stream>>>(deg, offs, blocksums);
    scan2_kernel<<<1, 256, 0, stream>>>(blocksums);
    scan3_kernel<<<(N_NODES + 255) / 256, 256, 0, stream>>>(offs, blocksums,
                                                            cursor);
    fill_kernel<<<(N_EDGES + 255) / 256, 256, 0, stream>>>(ei, cursor, csr_src);
    packW_kernel<<<320, 256, 0, stream>>>(W1s, W2s, Wpk8);
    bounds_kernel<<<(N_GRAPHS + 1 + 255) / 256, 256, 0, stream>>>(batch, start);

    // h0 = x @ Wp + bp  -> bufA (interleaved)
    proj_kernel<<<(N_NODES + PROJ_CH - 1) / PROJ_CH, 256, 0, stream>>>(x, Wp, bp,
                                                                       bufA);

    // Invariant: bufA always holds current z (interleaved); bufB is scratch.
    const int MLP_BLOCKS = (N_NODES + 63) / 64;  // 1563
    for (int l = 0; l < LAYERS; l++) {
        float* lsums = sums + l * 512;
        float* lsumsq = lsums + 256;
        const float* psums = sums + (l - 1) * 512;  // valid only for l>0
        gather_kernel<<<(N_NODES + 3) / 4, 256, 0, stream>>>(
            offs, csr_src, bufA, bufB, eps, l,
            l > 0 ? psums : sums, l > 0 ? psums + 256 : sums,
            gammas + (l > 0 ? (l - 1) : 0) * HID,
            betas + (l > 0 ? (l - 1) : 0) * HID, l > 0 ? 1 : 0);
        fused_mlp_kernel<<<MLP_BLOCKS, 256, 0, stream>>>(
            bufB, Wpk8 + (size_t)l * 16384, b1s + l * HID,
            Wpk8 + (size_t)(5 + l) * 16384, b2s + l * HID, bufA, N_NODES,
            lsums, lsumsq);
    }

    segpool_kernel<<<N_GRAPHS, 256, 0, stream>>>(
        bufA, start, sums + 4 * 512, sums + 4 * 512 + 256, gammas + 4 * HID,
        betas + 4 * HID, pooled);
    readout_kernel<<<N_GRAPHS, 256, 0, stream>>>(pooled, Wr1, br1, Wr2, br2, out);
}